// Round 11
// baseline (304.276 us; speedup 1.0000x reference)
//
#include <hip/hip_runtime.h>
#include <math.h>

#define M0 131072
#define NC 4096
#define FDIM 324   // 6*54
#define APW 8      // atoms per wave (sorted idx -> mostly same crystal)

// ---- asm LDS ops. NO "memory" clobbers anywhere: asm volatile statements are
// ordered among themselves, and the per-wave DS pipe executes in order, which
// is all the write->read phase ordering needs (buffers are wave-private).
// Keeping clobbers out lets weight s_loads stay cached across phases/atoms.
#define DSR128(dst, addr, OFF)                                                 \
  asm volatile("ds_read_b128 %0, %1 offset:" #OFF "\n\t"                       \
               "s_waitcnt lgkmcnt(0)"                                          \
               : "=v"(dst) : "v"(addr))

#define DSR2X64(dst, addr, O0, O1)                                             \
  asm volatile("ds_read2_b64 %0, %1 offset0:" #O0 " offset1:" #O1 "\n\t"       \
               "s_waitcnt lgkmcnt(0)"                                          \
               : "=v"(dst) : "v"(addr))

#define DSR32(dst, addr, OFF)                                                  \
  asm volatile("ds_read_b32 %0, %1 offset:" #OFF "\n\t"                        \
               "s_waitcnt lgkmcnt(0)"                                          \
               : "=v"(dst) : "v"(addr))

#define DSW64(addr, val)                                                       \
  asm volatile("ds_write_b64 %0, %1" :: "v"(addr), "v"(val))

#define DSW32(addr, val)                                                       \
  asm volatile("ds_write_b32 %0, %1" :: "v"(addr), "v"(val))

// Consume one 4-float chunk (window-relative floats 4M..4M+3) into
// acc[NOUT][NPOS]; weights stride wstride. All indices compile-time.
template<int M, int NOUT, int NPOS>
__device__ __forceinline__ void consume(const float4 f, float (&acc)[NOUT][NPOS],
                                        const float* __restrict__ w, const int wstride) {
    const float fi[4] = {f.x, f.y, f.z, f.w};
    #pragma unroll
    for (int i = 0; i < 4; ++i) {
        #pragma unroll
        for (int j = 0; j < NPOS; ++j) {
            const int k = 4 * M + i - j;
            if (k >= 0 && k < 20) {
                #pragma unroll
                for (int c = 0; c < NOUT; ++c)
                    acc[c][j] = fmaf(fi[i], w[c * wstride + k], acc[c][j]);
            }
        }
    }
}

// -------- Kernel 1: per-atom conv pipeline + register segment accumulation ----
__global__ __launch_bounds__(256, 8) void atom_kernel(
    const float* __restrict__ oh_g,    // [M0,92]
    const float* __restrict__ env_g,   // [M0,55]
    const int*   __restrict__ idx_g,   // [M0] sorted
    const float* __restrict__ wA, const float* __restrict__ bA,  // [3*20],[3]
    const float* __restrict__ w1, const float* __restrict__ b1,  // [3*20],[3]
    const float* __restrict__ w2, const float* __restrict__ b2,  // [6*3*20],[6]
    float* __restrict__ sums,          // [NC,324]
    float* __restrict__ counts)        // [NC]
{
    __shared__ __align__(16) float s_total[4][280];   // concat(atom[219], env[55]) = 274
    __shared__ __align__(16) float s_one1[4][384];    // conv1 pooled [3][128]; first 92 = one-hot scratch

    const int wave = threadIdx.x >> 6;
    const int lane = threadIdx.x & 63;

    float* total = s_total[wave];
    float* one1  = s_one1[wave];
    float* oh    = one1;                   // scratch alias: one-hot row [92]

    const unsigned tot_b = (unsigned)(size_t)total;
    const unsigned oh_b  = (unsigned)(size_t)oh;
    const unsigned one_b = (unsigned)(size_t)one1;

    const int wbase = (blockIdx.x * 4 + wave) * APW;

    float fa[6] = {0.f, 0.f, 0.f, 0.f, 0.f, 0.f};   // per-lane feature accum
    float cnt = 0.f;
    int cur = idx_g[wbase];

    for (int it = 0; it < APW; ++it) {
        const int atom = wbase + it;
        const int cry = idx_g[atom];                  // wave-uniform
        if (cry != cur) {                             // uniform branch: flush
            if (lane < 54) {
                float* dst = sums + (size_t)cur * FDIM + lane;
                #pragma unroll
                for (int c2 = 0; c2 < 6; ++c2) {
                    atomicAdd(dst + c2 * 54, fa[c2]);
                    fa[c2] = 0.f;
                }
            }
            if (lane == 0) atomicAdd(&counts[cur], cnt);
            cnt = 0.f;
            cur = cry;
        }

        // ---- Phase A: load one-hot (92) and env (55) into LDS (asm writes) ----
        if (lane < 46) {
            const float2 v = *reinterpret_cast<const float2*>(oh_g + (size_t)atom * 92 + 2 * lane);
            DSW64(oh_b + (unsigned)lane * 8u, v);
        }
        if (lane < 55) {
            const float e = env_g[(size_t)atom * 55 + lane];
            DSW32(tot_b + (219u + (unsigned)lane) * 4u, e);
        }

        // ---- Phase B: conva -> relu -> total[0..218]  (37 lanes x 2 pos) ----
        if (lane < 37) {
            const int p2 = 2 * lane;
            float acc[3][2];
            #pragma unroll
            for (int c = 0; c < 3; ++c) { acc[c][0] = bA[c]; acc[c][1] = bA[c]; }
            const unsigned a = oh_b + (unsigned)lane * 8u;
            float4 f;
            DSR2X64(f, a, 0, 1);   consume<0, 3, 2>(f, acc, wA, 20);
            DSR2X64(f, a, 2, 3);   consume<1, 3, 2>(f, acc, wA, 20);
            DSR2X64(f, a, 4, 5);   consume<2, 3, 2>(f, acc, wA, 20);
            DSR2X64(f, a, 6, 7);   consume<3, 3, 2>(f, acc, wA, 20);
            DSR2X64(f, a, 8, 9);   consume<4, 3, 2>(f, acc, wA, 20);
            float f20;
            DSR32(f20, a, 80);     // window float 20: k=19 for position p2+1
            #pragma unroll
            for (int c = 0; c < 3; ++c) acc[c][1] = fmaf(f20, wA[c * 20 + 19], acc[c][1]);

            const unsigned tb = tot_b + (unsigned)p2 * 4u;
            DSW32(tb,            fmaxf(acc[0][0], 0.f));
            DSW32(tb +  73u*4u,  fmaxf(acc[1][0], 0.f));
            DSW32(tb + 146u*4u,  fmaxf(acc[2][0], 0.f));
            if (p2 + 1 < 73) {
                DSW32(tb + 4u,           fmaxf(acc[0][1], 0.f));
                DSW32(tb + 74u*4u,       fmaxf(acc[1][1], 0.f));
                DSW32(tb + 147u*4u,      fmaxf(acc[2][1], 0.f));
            }
        }

        // ---- Phase C: conv1 (1->3,K=20)+relu+maxpool2 -> one1[3][128] ----
        // lane q -> pooled {2q,2q+1} (unpooled 4q..4q+3); 6 x ds_read_b128.
        // q=63: pooled 127 is garbage -> dead slot one1[c*128+127].
        {
            float acc[3][4];
            #pragma unroll
            for (int c = 0; c < 3; ++c) {
                const float b = b1[c];
                #pragma unroll
                for (int j = 0; j < 4; ++j) acc[c][j] = b;
            }
            const unsigned a = tot_b + (unsigned)lane * 16u;
            float4 f;
            DSR128(f, a, 0);    consume<0, 3, 4>(f, acc, w1, 20);
            DSR128(f, a, 16);   consume<1, 3, 4>(f, acc, w1, 20);
            DSR128(f, a, 32);   consume<2, 3, 4>(f, acc, w1, 20);
            DSR128(f, a, 48);   consume<3, 3, 4>(f, acc, w1, 20);
            DSR128(f, a, 64);   consume<4, 3, 4>(f, acc, w1, 20);
            DSR128(f, a, 80);   consume<5, 3, 4>(f, acc, w1, 20);
            #pragma unroll
            for (int c = 0; c < 3; ++c) {
                float2 st;
                st.x = fmaxf(fmaxf(acc[c][0], acc[c][1]), 0.f);
                st.y = fmaxf(fmaxf(acc[c][2], acc[c][3]), 0.f);
                DSW64(one_b + ((unsigned)c * 128u + 2u * (unsigned)lane) * 4u, st);
            }
        }

        // ---- Phase D: conv2 (3->6,K=20)+relu+maxpool2 -> fa[6] accumulate ----
        if (lane < 54) {
            float acc[6][2];
            #pragma unroll
            for (int c2 = 0; c2 < 6; ++c2) { acc[c2][0] = b2[c2]; acc[c2][1] = acc[c2][0]; }
            #pragma unroll
            for (int ch = 0; ch < 3; ++ch) {
                const unsigned a = one_b + (unsigned)ch * 512u + (unsigned)lane * 8u;
                const float* wch = w2 + ch * 20;     // index c2*60 + k
                float4 f;
                DSR2X64(f, a, 0, 1);   consume<0, 6, 2>(f, acc, wch, 60);
                DSR2X64(f, a, 2, 3);   consume<1, 6, 2>(f, acc, wch, 60);
                DSR2X64(f, a, 4, 5);   consume<2, 6, 2>(f, acc, wch, 60);
                DSR2X64(f, a, 6, 7);   consume<3, 6, 2>(f, acc, wch, 60);
                DSR2X64(f, a, 8, 9);   consume<4, 6, 2>(f, acc, wch, 60);
                float f20;
                DSR32(f20, a, 80);
                #pragma unroll
                for (int c2 = 0; c2 < 6; ++c2)
                    acc[c2][1] = fmaf(f20, wch[c2 * 60 + 19], acc[c2][1]);
            }
            #pragma unroll
            for (int c2 = 0; c2 < 6; ++c2)
                fa[c2] += fmaxf(fmaxf(acc[c2][0], acc[c2][1]), 0.f);
        }
        cnt += 1.f;
    }

    // ---- final flush ----
    if (lane < 54) {
        float* dst = sums + (size_t)cur * FDIM + lane;
        #pragma unroll
        for (int c2 = 0; c2 < 6; ++c2) atomicAdd(dst + c2 * 54, fa[c2]);
    }
    if (lane == 0) atomicAdd(&counts[cur], cnt);
}

// -------- Kernel 2: per-crystal mean+relu, 324->32 softplus, 32->1 ----------
__global__ __launch_bounds__(64) void head_kernel(
    const float* __restrict__ sums, const float* __restrict__ counts,
    const float* __restrict__ lin_w, const float* __restrict__ lin_b,
    const float* __restrict__ lin1_w, const float* __restrict__ lin1_b,
    float* __restrict__ out)
{
    __shared__ float p[FDIM];
    const int c = blockIdx.x;
    const int lane = threadIdx.x;
    const float inv = 1.0f / fmaxf(counts[c], 1.0f);
    for (int i = lane; i < FDIM; i += 64)
        p[i] = fmaxf(sums[(size_t)c * FDIM + i] * inv, 0.f);
    __syncthreads();

    float r = 0.f;
    if (lane < 32) {
        float acc = lin_b[lane];
        const float* wrow = lin_w + lane * FDIM;
        #pragma unroll 4
        for (int i = 0; i < FDIM; ++i) acc = fmaf(p[i], wrow[i], acc);
        const float sp = (acc > 0.f) ? acc + log1pf(expf(-acc)) : log1pf(expf(acc));
        r = sp * lin1_w[lane];
    }
    #pragma unroll
    for (int off = 16; off; off >>= 1) r += __shfl_down(r, off);
    if (lane == 0) out[c] = r + lin1_b[0];
}

extern "C" void kernel_launch(void* const* d_in, const int* in_sizes, int n_in,
                              void* d_out, int out_size, void* d_ws, size_t ws_size,
                              hipStream_t stream) {
    (void)in_sizes; (void)n_in; (void)out_size; (void)ws_size;
    const float* oh    = (const float*)d_in[0];
    const float* env   = (const float*)d_in[1];
    const int*   idx   = (const int*)  d_in[2];
    // d_in[3] = num_segments (constant 4096)
    const float* wA    = (const float*)d_in[4];
    const float* bA    = (const float*)d_in[5];
    const float* w1    = (const float*)d_in[6];
    const float* b1    = (const float*)d_in[7];
    const float* w2    = (const float*)d_in[8];
    const float* b2    = (const float*)d_in[9];
    const float* lin_w = (const float*)d_in[10];
    const float* lin_b = (const float*)d_in[11];
    const float* lin1_w= (const float*)d_in[12];
    const float* lin1_b= (const float*)d_in[13];

    float* sums   = (float*)d_ws;             // [NC*FDIM]
    float* counts = sums + (size_t)NC * FDIM; // [NC]

    hipMemsetAsync(d_ws, 0, ((size_t)NC * FDIM + NC) * sizeof(float), stream);

    atom_kernel<<<M0 / (4 * APW), 256, 0, stream>>>(oh, env, idx, wA, bA, w1, b1,
                                                    w2, b2, sums, counts);
    head_kernel<<<NC, 64, 0, stream>>>(sums, counts, lin_w, lin_b, lin1_w, lin1_b,
                                       (float*)d_out);
}

// Round 12
// 250.753 us; speedup vs baseline: 1.2134x; 1.2134x over previous
//
#include <hip/hip_runtime.h>
#include <math.h>

#define M0 131072
#define NC 4096
#define FDIM 324   // 6*54
#define APW 8      // atoms per wave (sorted idx -> mostly same crystal)

// ---- batched asm LDS ops (no "memory" clobbers; asm volatile stays ordered,
// per-wave DS pipe is in-order, buffers are wave-private / block-stable) ----

// 21-float window at 8B-aligned addr: 5x ds_read2_b64 + 1x b32, one wait.
#define DSWIN21(w0, w1, w2, w3, w4, g, addr)                                   \
  asm volatile("ds_read2_b64 %0, %6 offset0:0 offset1:1\n\t"                   \
               "ds_read2_b64 %1, %6 offset0:2 offset1:3\n\t"                   \
               "ds_read2_b64 %2, %6 offset0:4 offset1:5\n\t"                   \
               "ds_read2_b64 %3, %6 offset0:6 offset1:7\n\t"                   \
               "ds_read2_b64 %4, %6 offset0:8 offset1:9\n\t"                   \
               "ds_read_b32 %5, %6 offset:80\n\t"                              \
               "s_waitcnt lgkmcnt(0)"                                          \
               : "=v"(w0), "=v"(w1), "=v"(w2), "=v"(w3), "=v"(w4), "=v"(g)     \
               : "v"(addr))

// 24-float window at 16B-aligned addr: 6x ds_read_b128, one wait.
#define DSWIN24(w0, w1, w2, w3, w4, w5, addr)                                  \
  asm volatile("ds_read_b128 %0, %6 offset:0\n\t"                              \
               "ds_read_b128 %1, %6 offset:16\n\t"                             \
               "ds_read_b128 %2, %6 offset:32\n\t"                             \
               "ds_read_b128 %3, %6 offset:48\n\t"                             \
               "ds_read_b128 %4, %6 offset:64\n\t"                             \
               "ds_read_b128 %5, %6 offset:80\n\t"                             \
               "s_waitcnt lgkmcnt(0)"                                          \
               : "=v"(w0), "=v"(w1), "=v"(w2), "=v"(w3), "=v"(w4), "=v"(w5)    \
               : "v"(addr))

// 20 weights (16B-aligned): 5x ds_read_b128, one wait. Uniform addr = broadcast.
#define DSWQ5(q0, q1, q2, q3, q4, addr)                                        \
  asm volatile("ds_read_b128 %0, %5 offset:0\n\t"                              \
               "ds_read_b128 %1, %5 offset:16\n\t"                             \
               "ds_read_b128 %2, %5 offset:32\n\t"                             \
               "ds_read_b128 %3, %5 offset:48\n\t"                             \
               "ds_read_b128 %4, %5 offset:64\n\t"                             \
               "s_waitcnt lgkmcnt(0)"                                          \
               : "=v"(q0), "=v"(q1), "=v"(q2), "=v"(q3), "=v"(q4)              \
               : "v"(addr))

#define DSW64(addr, val)                                                       \
  asm volatile("ds_write_b64 %0, %1" :: "v"(addr), "v"(val))

#define DSW32(addr, val)                                                       \
  asm volatile("ds_write_b32 %0, %1" :: "v"(addr), "v"(val))

// ---- compile-time window element accessors ----
template<int J>
__device__ __forceinline__ float el21(const float4 (&W)[5], float g) {
    if constexpr (J >= 20) return g;
    else {
        constexpr int q = J >> 2, r = J & 3;
        if constexpr (r == 0) return W[q].x;
        else if constexpr (r == 1) return W[q].y;
        else if constexpr (r == 2) return W[q].z;
        else return W[q].w;
    }
}
template<int J>
__device__ __forceinline__ float el24(const float4 (&W)[6]) {
    constexpr int q = J >> 2, r = J & 3;
    if constexpr (r == 0) return W[q].x;
    else if constexpr (r == 1) return W[q].y;
    else if constexpr (r == 2) return W[q].z;
    else return W[q].w;
}

// 4 k-steps x 2 positions against one weight quad (k = K0..K0+3).
template<int K0>
__device__ __forceinline__ void fq2(const float4 wq, const float4 (&W)[5], float g,
                                    float& a0, float& a1) {
    a0 = fmaf(el21<K0 + 0>(W, g), wq.x, a0); a1 = fmaf(el21<K0 + 1>(W, g), wq.x, a1);
    a0 = fmaf(el21<K0 + 1>(W, g), wq.y, a0); a1 = fmaf(el21<K0 + 2>(W, g), wq.y, a1);
    a0 = fmaf(el21<K0 + 2>(W, g), wq.z, a0); a1 = fmaf(el21<K0 + 3>(W, g), wq.z, a1);
    a0 = fmaf(el21<K0 + 3>(W, g), wq.w, a0); a1 = fmaf(el21<K0 + 4>(W, g), wq.w, a1);
}
// 4 k-steps x 4 positions against one weight quad.
template<int K0>
__device__ __forceinline__ void fq4(const float4 wq, const float4 (&W)[6], float (&a)[4]) {
    a[0] = fmaf(el24<K0 + 0>(W), wq.x, a[0]); a[1] = fmaf(el24<K0 + 1>(W), wq.x, a[1]);
    a[2] = fmaf(el24<K0 + 2>(W), wq.x, a[2]); a[3] = fmaf(el24<K0 + 3>(W), wq.x, a[3]);
    a[0] = fmaf(el24<K0 + 1>(W), wq.y, a[0]); a[1] = fmaf(el24<K0 + 2>(W), wq.y, a[1]);
    a[2] = fmaf(el24<K0 + 3>(W), wq.y, a[2]); a[3] = fmaf(el24<K0 + 4>(W), wq.y, a[3]);
    a[0] = fmaf(el24<K0 + 2>(W), wq.z, a[0]); a[1] = fmaf(el24<K0 + 3>(W), wq.z, a[1]);
    a[2] = fmaf(el24<K0 + 4>(W), wq.z, a[2]); a[3] = fmaf(el24<K0 + 5>(W), wq.z, a[3]);
    a[0] = fmaf(el24<K0 + 3>(W), wq.w, a[0]); a[1] = fmaf(el24<K0 + 4>(W), wq.w, a[1]);
    a[2] = fmaf(el24<K0 + 5>(W), wq.w, a[2]); a[3] = fmaf(el24<K0 + 6>(W), wq.w, a[3]);
}

// -------- Kernel 1: per-atom conv pipeline + register segment accumulation ----
__global__ __launch_bounds__(256, 4) void atom_kernel(
    const float* __restrict__ oh_g,    // [M0,92]
    const float* __restrict__ env_g,   // [M0,55]
    const int*   __restrict__ idx_g,   // [M0] sorted
    const float* __restrict__ wA, const float* __restrict__ bA,  // [3*20],[3]
    const float* __restrict__ w1, const float* __restrict__ b1,  // [3*20],[3]
    const float* __restrict__ w2, const float* __restrict__ b2,  // [6*3*20],[6]
    float* __restrict__ sums,          // [NC,324]
    float* __restrict__ counts)        // [NC]
{
    __shared__ __align__(16) float w_lds[480];        // wA[0:60] w1[60:120] w2[120:480]
    __shared__ __align__(16) float s_total[4][280];   // concat(atom[219], env[55]) = 274
    __shared__ __align__(16) float s_one1[4][384];    // conv1 pooled [3][128]; first 92 = scratch

    const int wave = threadIdx.x >> 6;
    const int lane = threadIdx.x & 63;
    const int tid  = threadIdx.x;

    const unsigned w_b   = (unsigned)(size_t)w_lds;
    const unsigned tot_b = (unsigned)(size_t)s_total[wave];
    const unsigned one_b = (unsigned)(size_t)s_one1[wave];
    const unsigned oh_b  = one_b;                     // scratch alias

    // ---- stage all conv weights into LDS once per block (asm writes: no DCE) ----
    for (int i = tid; i < 360; i += 256) DSW32(w_b + (120u + (unsigned)i) * 4u, w2[i]);
    if (tid < 60)       DSW32(w_b + (unsigned)tid * 4u, wA[tid]);
    else if (tid < 120) DSW32(w_b + (unsigned)tid * 4u, w1[tid - 60]);
    __syncthreads();

    const int wbase = (blockIdx.x * 4 + wave) * APW;

    float fa[6] = {0.f, 0.f, 0.f, 0.f, 0.f, 0.f};
    float cnt = 0.f;
    int cur = idx_g[wbase];

    for (int it = 0; it < APW; ++it) {
        const int atom = wbase + it;
        const int cry = idx_g[atom];                  // wave-uniform
        if (cry != cur) {                             // uniform branch: flush
            if (lane < 54) {
                float* dst = sums + (size_t)cur * FDIM + lane;
                #pragma unroll
                for (int c2 = 0; c2 < 6; ++c2) {
                    atomicAdd(dst + c2 * 54, fa[c2]);
                    fa[c2] = 0.f;
                }
            }
            if (lane == 0) atomicAdd(&counts[cur], cnt);
            cnt = 0.f;
            cur = cry;
        }

        // ---- Phase A: one-hot (92) + env (55) into LDS ----
        if (lane < 46) {
            const float2 v = *reinterpret_cast<const float2*>(oh_g + (size_t)atom * 92 + 2 * lane);
            DSW64(oh_b + (unsigned)lane * 8u, v);
        }
        if (lane < 55) {
            const float e = env_g[(size_t)atom * 55 + lane];
            DSW32(tot_b + (219u + (unsigned)lane) * 4u, e);
        }

        // ---- Phase B: conva -> relu -> total[0..218]  (37 lanes x 2 pos) ----
        if (lane < 37) {
            float4 W[5]; float g;
            DSWIN21(W[0], W[1], W[2], W[3], W[4], g, oh_b + (unsigned)lane * 8u);
            const unsigned p2 = 2u * (unsigned)lane;
            #pragma unroll
            for (int c = 0; c < 3; ++c) {
                float4 wq[5];
                DSWQ5(wq[0], wq[1], wq[2], wq[3], wq[4], w_b + (unsigned)c * 80u);
                float a0 = bA[c], a1 = a0;
                fq2<0>(wq[0], W, g, a0, a1);  fq2<4>(wq[1], W, g, a0, a1);
                fq2<8>(wq[2], W, g, a0, a1);  fq2<12>(wq[3], W, g, a0, a1);
                fq2<16>(wq[4], W, g, a0, a1);
                const unsigned tb = tot_b + (73u * (unsigned)c + p2) * 4u;
                DSW32(tb, fmaxf(a0, 0.f));
                if (p2 + 1 < 73) DSW32(tb + 4u, fmaxf(a1, 0.f));
            }
        }

        // ---- Phase C: conv1 + relu + maxpool2 -> one1[3][128] (64 lanes x 4 pos) ----
        // lane q: unpooled 4q..4q+3 -> pooled {2q,2q+1}; q=63 garbage -> dead slot 127.
        {
            float4 W[6];
            DSWIN24(W[0], W[1], W[2], W[3], W[4], W[5], tot_b + (unsigned)lane * 16u);
            #pragma unroll
            for (int c = 0; c < 3; ++c) {
                float4 wq[5];
                DSWQ5(wq[0], wq[1], wq[2], wq[3], wq[4], w_b + 240u + (unsigned)c * 80u);
                float a4[4] = {b1[c], b1[c], b1[c], b1[c]};
                fq4<0>(wq[0], W, a4);  fq4<4>(wq[1], W, a4);  fq4<8>(wq[2], W, a4);
                fq4<12>(wq[3], W, a4); fq4<16>(wq[4], W, a4);
                float2 st;
                st.x = fmaxf(fmaxf(a4[0], a4[1]), 0.f);
                st.y = fmaxf(fmaxf(a4[2], a4[3]), 0.f);
                DSW64(one_b + ((unsigned)c * 128u + 2u * (unsigned)lane) * 4u, st);
            }
        }

        // ---- Phase D: conv2 + relu + maxpool2 -> fa[6] accumulate (54 lanes) ----
        if (lane < 54) {
            float acc0[6], acc1[6];
            #pragma unroll
            for (int c2 = 0; c2 < 6; ++c2) { acc0[c2] = b2[c2]; acc1[c2] = acc0[c2]; }
            #pragma unroll
            for (int ch = 0; ch < 3; ++ch) {
                float4 W[5]; float g;
                DSWIN21(W[0], W[1], W[2], W[3], W[4], g,
                        one_b + (unsigned)ch * 512u + (unsigned)lane * 8u);
                #pragma unroll
                for (int c2 = 0; c2 < 6; ++c2) {
                    float4 wq[5];
                    DSWQ5(wq[0], wq[1], wq[2], wq[3], wq[4],
                          w_b + 480u + ((unsigned)c2 * 3u + (unsigned)ch) * 80u);
                    fq2<0>(wq[0], W, g, acc0[c2], acc1[c2]);
                    fq2<4>(wq[1], W, g, acc0[c2], acc1[c2]);
                    fq2<8>(wq[2], W, g, acc0[c2], acc1[c2]);
                    fq2<12>(wq[3], W, g, acc0[c2], acc1[c2]);
                    fq2<16>(wq[4], W, g, acc0[c2], acc1[c2]);
                }
            }
            #pragma unroll
            for (int c2 = 0; c2 < 6; ++c2)
                fa[c2] += fmaxf(fmaxf(acc0[c2], acc1[c2]), 0.f);
        }
        cnt += 1.f;
    }

    // ---- final flush ----
    if (lane < 54) {
        float* dst = sums + (size_t)cur * FDIM + lane;
        #pragma unroll
        for (int c2 = 0; c2 < 6; ++c2) atomicAdd(dst + c2 * 54, fa[c2]);
    }
    if (lane == 0) atomicAdd(&counts[cur], cnt);
}

// -------- Kernel 2: per-crystal mean+relu, 324->32 softplus, 32->1 ----------
__global__ __launch_bounds__(64) void head_kernel(
    const float* __restrict__ sums, const float* __restrict__ counts,
    const float* __restrict__ lin_w, const float* __restrict__ lin_b,
    const float* __restrict__ lin1_w, const float* __restrict__ lin1_b,
    float* __restrict__ out)
{
    __shared__ float p[FDIM];
    const int c = blockIdx.x;
    const int lane = threadIdx.x;
    const float inv = 1.0f / fmaxf(counts[c], 1.0f);
    for (int i = lane; i < FDIM; i += 64)
        p[i] = fmaxf(sums[(size_t)c * FDIM + i] * inv, 0.f);
    __syncthreads();

    float r = 0.f;
    if (lane < 32) {
        float acc = lin_b[lane];
        const float* wrow = lin_w + lane * FDIM;
        #pragma unroll 4
        for (int i = 0; i < FDIM; ++i) acc = fmaf(p[i], wrow[i], acc);
        const float sp = (acc > 0.f) ? acc + log1pf(expf(-acc)) : log1pf(expf(acc));
        r = sp * lin1_w[lane];
    }
    #pragma unroll
    for (int off = 16; off; off >>= 1) r += __shfl_down(r, off);
    if (lane == 0) out[c] = r + lin1_b[0];
}

extern "C" void kernel_launch(void* const* d_in, const int* in_sizes, int n_in,
                              void* d_out, int out_size, void* d_ws, size_t ws_size,
                              hipStream_t stream) {
    (void)in_sizes; (void)n_in; (void)out_size; (void)ws_size;
    const float* oh    = (const float*)d_in[0];
    const float* env   = (const float*)d_in[1];
    const int*   idx   = (const int*)  d_in[2];
    // d_in[3] = num_segments (constant 4096)
    const float* wA    = (const float*)d_in[4];
    const float* bA    = (const float*)d_in[5];
    const float* w1    = (const float*)d_in[6];
    const float* b1    = (const float*)d_in[7];
    const float* w2    = (const float*)d_in[8];
    const float* b2    = (const float*)d_in[9];
    const float* lin_w = (const float*)d_in[10];
    const float* lin_b = (const float*)d_in[11];
    const float* lin1_w= (const float*)d_in[12];
    const float* lin1_b= (const float*)d_in[13];

    float* sums   = (float*)d_ws;             // [NC*FDIM]
    float* counts = sums + (size_t)NC * FDIM; // [NC]

    hipMemsetAsync(d_ws, 0, ((size_t)NC * FDIM + NC) * sizeof(float), stream);

    atom_kernel<<<M0 / (4 * APW), 256, 0, stream>>>(oh, env, idx, wA, bA, w1, b1,
                                                    w2, b2, sums, counts);
    head_kernel<<<NC, 64, 0, stream>>>(sums, counts, lin_w, lin_b, lin1_w, lin1_b,
                                       (float*)d_out);
}

// Round 15
// 249.289 us; speedup vs baseline: 1.2206x; 1.0059x over previous
//
#include <hip/hip_runtime.h>
#include <math.h>

#define M0 131072
#define NC 4096
#define FDIM 324   // 6*54
#define APW 4      // atoms per wave (sorted idx -> mostly same crystal)

// ---- batched asm LDS ops, wait INSIDE each block (proven-correct R12 form:
// consumers are dataflow-gated on outputs, which complete at the in-block wait;
// no separate wait statement exists for the scheduler to hoist past).
#define DSWIN21(w0, w1, w2, w3, w4, g, addr)                                   \
  asm volatile("ds_read2_b64 %0, %6 offset0:0 offset1:1\n\t"                   \
               "ds_read2_b64 %1, %6 offset0:2 offset1:3\n\t"                   \
               "ds_read2_b64 %2, %6 offset0:4 offset1:5\n\t"                   \
               "ds_read2_b64 %3, %6 offset0:6 offset1:7\n\t"                   \
               "ds_read2_b64 %4, %6 offset0:8 offset1:9\n\t"                   \
               "ds_read_b32 %5, %6 offset:80\n\t"                              \
               "s_waitcnt lgkmcnt(0)"                                          \
               : "=v"(w0), "=v"(w1), "=v"(w2), "=v"(w3), "=v"(w4), "=v"(g)     \
               : "v"(addr))

#define DSWIN24(w0, w1, w2, w3, w4, w5, addr)                                  \
  asm volatile("ds_read_b128 %0, %6 offset:0\n\t"                              \
               "ds_read_b128 %1, %6 offset:16\n\t"                             \
               "ds_read_b128 %2, %6 offset:32\n\t"                             \
               "ds_read_b128 %3, %6 offset:48\n\t"                             \
               "ds_read_b128 %4, %6 offset:64\n\t"                             \
               "ds_read_b128 %5, %6 offset:80\n\t"                             \
               "s_waitcnt lgkmcnt(0)"                                          \
               : "=v"(w0), "=v"(w1), "=v"(w2), "=v"(w3), "=v"(w4), "=v"(w5)    \
               : "v"(addr))

#define DSWQ5(q0, q1, q2, q3, q4, addr)                                        \
  asm volatile("ds_read_b128 %0, %5 offset:0\n\t"                              \
               "ds_read_b128 %1, %5 offset:16\n\t"                             \
               "ds_read_b128 %2, %5 offset:32\n\t"                             \
               "ds_read_b128 %3, %5 offset:48\n\t"                             \
               "ds_read_b128 %4, %5 offset:64\n\t"                             \
               "s_waitcnt lgkmcnt(0)"                                          \
               : "=v"(q0), "=v"(q1), "=v"(q2), "=v"(q3), "=v"(q4)              \
               : "v"(addr))

#define DSW64(addr, val)  asm volatile("ds_write_b64 %0, %1" :: "v"(addr), "v"(val))
#define DSW32(addr, val)  asm volatile("ds_write_b32 %0, %1" :: "v"(addr), "v"(val))

// ---- compile-time window element accessors ----
template<int J>
__device__ __forceinline__ float el21(const float4 (&W)[5], float g) {
    if constexpr (J >= 20) return g;
    else {
        constexpr int q = J >> 2, r = J & 3;
        if constexpr (r == 0) return W[q].x;
        else if constexpr (r == 1) return W[q].y;
        else if constexpr (r == 2) return W[q].z;
        else return W[q].w;
    }
}
template<int J>
__device__ __forceinline__ float el24(const float4 (&W)[6]) {
    constexpr int q = J >> 2, r = J & 3;
    if constexpr (r == 0) return W[q].x;
    else if constexpr (r == 1) return W[q].y;
    else if constexpr (r == 2) return W[q].z;
    else return W[q].w;
}

// 4 k-steps x 2 positions against one weight quad (k = K0..K0+3).
template<int K0>
__device__ __forceinline__ void fq2(const float4 wq, const float4 (&W)[5], float g,
                                    float& a0, float& a1) {
    a0 = fmaf(el21<K0 + 0>(W, g), wq.x, a0); a1 = fmaf(el21<K0 + 1>(W, g), wq.x, a1);
    a0 = fmaf(el21<K0 + 1>(W, g), wq.y, a0); a1 = fmaf(el21<K0 + 2>(W, g), wq.y, a1);
    a0 = fmaf(el21<K0 + 2>(W, g), wq.z, a0); a1 = fmaf(el21<K0 + 3>(W, g), wq.z, a1);
    a0 = fmaf(el21<K0 + 3>(W, g), wq.w, a0); a1 = fmaf(el21<K0 + 4>(W, g), wq.w, a1);
}
// 4 k-steps x 4 positions against one weight quad.
template<int K0>
__device__ __forceinline__ void fq4(const float4 wq, const float4 (&W)[6], float (&a)[4]) {
    a[0] = fmaf(el24<K0 + 0>(W), wq.x, a[0]); a[1] = fmaf(el24<K0 + 1>(W), wq.x, a[1]);
    a[2] = fmaf(el24<K0 + 2>(W), wq.x, a[2]); a[3] = fmaf(el24<K0 + 3>(W), wq.x, a[3]);
    a[0] = fmaf(el24<K0 + 1>(W), wq.y, a[0]); a[1] = fmaf(el24<K0 + 2>(W), wq.y, a[1]);
    a[2] = fmaf(el24<K0 + 3>(W), wq.y, a[2]); a[3] = fmaf(el24<K0 + 4>(W), wq.y, a[3]);
    a[0] = fmaf(el24<K0 + 2>(W), wq.z, a[0]); a[1] = fmaf(el24<K0 + 3>(W), wq.z, a[1]);
    a[2] = fmaf(el24<K0 + 4>(W), wq.z, a[2]); a[3] = fmaf(el24<K0 + 5>(W), wq.z, a[3]);
    a[0] = fmaf(el24<K0 + 3>(W), wq.w, a[0]); a[1] = fmaf(el24<K0 + 4>(W), wq.w, a[1]);
    a[2] = fmaf(el24<K0 + 5>(W), wq.w, a[2]); a[3] = fmaf(el24<K0 + 6>(W), wq.w, a[3]);
}

// -------- Kernel 1: per-atom conv pipeline + register segment accumulation ----
__global__ __launch_bounds__(256, 8) void atom_kernel(
    const float* __restrict__ oh_g,    // [M0,92]
    const float* __restrict__ env_g,   // [M0,55]
    const int*   __restrict__ idx_g,   // [M0] sorted
    const float* __restrict__ wA, const float* __restrict__ bA,  // [3*20],[3]
    const float* __restrict__ w1, const float* __restrict__ b1,  // [3*20],[3]
    const float* __restrict__ w2, const float* __restrict__ b2,  // [6*3*20],[6]
    float* __restrict__ sums,          // [NC,324]
    float* __restrict__ counts)        // [NC]
{
    __shared__ __align__(16) float w_lds[480];        // wA[0:60] w1[60:120] w2[120:480]
    __shared__ __align__(16) float s_total[4][280];   // concat(atom[219], env[55]) = 274
    __shared__ __align__(16) float s_one1[4][384];    // conv1 pooled [3][128]; first 92 = scratch

    const int wave = threadIdx.x >> 6;
    const int lane = threadIdx.x & 63;
    const int tid  = threadIdx.x;

    const unsigned w_b   = (unsigned)(size_t)w_lds;
    const unsigned wD_b  = w_b + 480u;                // w2 bytes
    const unsigned tot_b = (unsigned)(size_t)s_total[wave];
    const unsigned one_b = (unsigned)(size_t)s_one1[wave];
    const unsigned oh_b  = one_b;                     // scratch alias

    // ---- stage all conv weights into LDS once per block (asm writes: no DCE) ----
    for (int i = tid; i < 360; i += 256) DSW32(w_b + (120u + (unsigned)i) * 4u, w2[i]);
    if (tid < 60)       DSW32(w_b + (unsigned)tid * 4u, wA[tid]);
    else if (tid < 120) DSW32(w_b + (unsigned)tid * 4u, w1[tid - 60]);
    __syncthreads();

    const int wbase = (blockIdx.x * 4 + wave) * APW;

    float fa[6] = {0.f, 0.f, 0.f, 0.f, 0.f, 0.f};
    float cnt = 0.f;
    int cur = idx_g[wbase];

    for (int it = 0; it < APW; ++it) {
        const int atom = wbase + it;
        const int cry = idx_g[atom];                  // wave-uniform
        if (cry != cur) {                             // uniform branch: flush
            if (lane < 54) {
                float* dst = sums + (size_t)cur * FDIM + lane;
                #pragma unroll
                for (int c2 = 0; c2 < 6; ++c2) {
                    atomicAdd(dst + c2 * 54, fa[c2]);
                    fa[c2] = 0.f;
                }
            }
            if (lane == 0) atomicAdd(&counts[cur], cnt);
            cnt = 0.f;
            cur = cry;
        }

        // ---- Phase A: one-hot (92) + env (55) into LDS ----
        if (lane < 46) {
            const float2 v = *reinterpret_cast<const float2*>(oh_g + (size_t)atom * 92 + 2 * lane);
            DSW64(oh_b + (unsigned)lane * 8u, v);
        }
        if (lane < 55) {
            const float e = env_g[(size_t)atom * 55 + lane];
            DSW32(tot_b + (219u + (unsigned)lane) * 4u, e);
        }

        // ---- Phase B: conva -> relu -> total[0..218]  (37 lanes x 2 pos) ----
        if (lane < 37) {
            float4 W[5]; float g;
            DSWIN21(W[0], W[1], W[2], W[3], W[4], g, oh_b + (unsigned)lane * 8u);
            const unsigned p2 = 2u * (unsigned)lane;
            #pragma unroll
            for (int c = 0; c < 3; ++c) {
                float4 wq[5];
                DSWQ5(wq[0], wq[1], wq[2], wq[3], wq[4], w_b + (unsigned)c * 80u);
                float a0 = bA[c], a1 = a0;
                fq2<0>(wq[0], W, g, a0, a1);  fq2<4>(wq[1], W, g, a0, a1);
                fq2<8>(wq[2], W, g, a0, a1);  fq2<12>(wq[3], W, g, a0, a1);
                fq2<16>(wq[4], W, g, a0, a1);
                const unsigned tb = tot_b + (73u * (unsigned)c + p2) * 4u;
                DSW32(tb, fmaxf(a0, 0.f));
                if (p2 + 1 < 73) DSW32(tb + 4u, fmaxf(a1, 0.f));
            }
        }

        // ---- Phase C: conv1 + relu + maxpool2 -> one1[3][128] (64 lanes x 4 pos) ----
        // lane q: unpooled 4q..4q+3 -> pooled {2q,2q+1}; q=63 garbage -> dead slot 127.
        {
            float4 W[6];
            DSWIN24(W[0], W[1], W[2], W[3], W[4], W[5], tot_b + (unsigned)lane * 16u);
            #pragma unroll
            for (int c = 0; c < 3; ++c) {
                float4 wq[5];
                DSWQ5(wq[0], wq[1], wq[2], wq[3], wq[4], w_b + 240u + (unsigned)c * 80u);
                float a4[4] = {b1[c], b1[c], b1[c], b1[c]};
                fq4<0>(wq[0], W, a4);  fq4<4>(wq[1], W, a4);  fq4<8>(wq[2], W, a4);
                fq4<12>(wq[3], W, a4); fq4<16>(wq[4], W, a4);
                float2 st;
                st.x = fmaxf(fmaxf(a4[0], a4[1]), 0.f);
                st.y = fmaxf(fmaxf(a4[2], a4[3]), 0.f);
                DSW64(one_b + ((unsigned)c * 128u + 2u * (unsigned)lane) * 4u, st);
            }
        }

        // ---- Phase D: conv2 + relu + maxpool2 -> fa[6] accumulate (54 lanes) ----
        if (lane < 54) {
            float acc0[6], acc1[6];
            #pragma unroll
            for (int c2 = 0; c2 < 6; ++c2) { acc0[c2] = b2[c2]; acc1[c2] = acc0[c2]; }
            #pragma unroll
            for (int ch = 0; ch < 3; ++ch) {
                float4 W[5]; float g;
                DSWIN21(W[0], W[1], W[2], W[3], W[4], g,
                        one_b + (unsigned)ch * 512u + (unsigned)lane * 8u);
                #pragma unroll
                for (int c2 = 0; c2 < 6; ++c2) {
                    float4 wq[5];
                    DSWQ5(wq[0], wq[1], wq[2], wq[3], wq[4],
                          wD_b + ((unsigned)c2 * 3u + (unsigned)ch) * 80u);
                    fq2<0>(wq[0], W, g, acc0[c2], acc1[c2]);
                    fq2<4>(wq[1], W, g, acc0[c2], acc1[c2]);
                    fq2<8>(wq[2], W, g, acc0[c2], acc1[c2]);
                    fq2<12>(wq[3], W, g, acc0[c2], acc1[c2]);
                    fq2<16>(wq[4], W, g, acc0[c2], acc1[c2]);
                }
            }
            #pragma unroll
            for (int c2 = 0; c2 < 6; ++c2)
                fa[c2] += fmaxf(fmaxf(acc0[c2], acc1[c2]), 0.f);
        }
        cnt += 1.f;
    }

    // ---- final flush ----
    if (lane < 54) {
        float* dst = sums + (size_t)cur * FDIM + lane;
        #pragma unroll
        for (int c2 = 0; c2 < 6; ++c2) atomicAdd(dst + c2 * 54, fa[c2]);
    }
    if (lane == 0) atomicAdd(&counts[cur], cnt);
}

// -------- Kernel 2: per-crystal mean+relu, 324->32 softplus, 32->1 ----------
__global__ __launch_bounds__(64) void head_kernel(
    const float* __restrict__ sums, const float* __restrict__ counts,
    const float* __restrict__ lin_w, const float* __restrict__ lin_b,
    const float* __restrict__ lin1_w, const float* __restrict__ lin1_b,
    float* __restrict__ out)
{
    __shared__ float p[FDIM];
    const int c = blockIdx.x;
    const int lane = threadIdx.x;
    const float inv = 1.0f / fmaxf(counts[c], 1.0f);
    for (int i = lane; i < FDIM; i += 64)
        p[i] = fmaxf(sums[(size_t)c * FDIM + i] * inv, 0.f);
    __syncthreads();

    float r = 0.f;
    if (lane < 32) {
        float acc = lin_b[lane];
        const float* wrow = lin_w + lane * FDIM;
        #pragma unroll 4
        for (int i = 0; i < FDIM; ++i) acc = fmaf(p[i], wrow[i], acc);
        const float sp = (acc > 0.f) ? acc + log1pf(expf(-acc)) : log1pf(expf(acc));
        r = sp * lin1_w[lane];
    }
    #pragma unroll
    for (int off = 16; off; off >>= 1) r += __shfl_down(r, off);
    if (lane == 0) out[c] = r + lin1_b[0];
}

extern "C" void kernel_launch(void* const* d_in, const int* in_sizes, int n_in,
                              void* d_out, int out_size, void* d_ws, size_t ws_size,
                              hipStream_t stream) {
    (void)in_sizes; (void)n_in; (void)out_size; (void)ws_size;
    const float* oh    = (const float*)d_in[0];
    const float* env   = (const float*)d_in[1];
    const int*   idx   = (const int*)  d_in[2];
    // d_in[3] = num_segments (constant 4096)
    const float* wA    = (const float*)d_in[4];
    const float* bA    = (const float*)d_in[5];
    const float* w1    = (const float*)d_in[6];
    const float* b1    = (const float*)d_in[7];
    const float* w2    = (const float*)d_in[8];
    const float* b2    = (const float*)d_in[9];
    const float* lin_w = (const float*)d_in[10];
    const float* lin_b = (const float*)d_in[11];
    const float* lin1_w= (const float*)d_in[12];
    const float* lin1_b= (const float*)d_in[13];

    float* sums   = (float*)d_ws;             // [NC*FDIM]
    float* counts = sums + (size_t)NC * FDIM; // [NC]

    hipMemsetAsync(d_ws, 0, ((size_t)NC * FDIM + NC) * sizeof(float), stream);

    atom_kernel<<<M0 / (4 * APW), 256, 0, stream>>>(oh, env, idx, wA, bA, w1, b1,
                                                    w2, b2, sums, counts);
    head_kernel<<<NC, 64, 0, stream>>>(sums, counts, lin_w, lin_b, lin1_w, lin1_b,
                                       (float*)d_out);
}